// Round 6
// baseline (503.194 us; speedup 1.0000x reference)
//
#include <hip/hip_runtime.h>
#include <hip/hip_fp16.h>

#define NLEVELS 16
#define BLOCK 256
#define PPT1 4      // points per thread, fp16 main pass-1
#define PPT 2       // points per thread, f32 fallback pass-1
#define CCHUNK 12288  // coarse LDS chunk entries (48 KB) -- lv0:1 chunk, lv1:3
#define PPT_C 8     // coarse points per thread
#define NCOARSE 2   // levels 0..NCOARSE-1 handled by the LDS-table kernel

struct HashParams {
    unsigned offs[NLEVELS + 1];  // per-level table offsets (entries)
    unsigned hsize[NLEVELS];     // per-level table size (entries)
    unsigned hash_bits;          // bit l set -> hash path for level l (all, this config)
    unsigned pow2_bits;          // bit l set -> hsize[l] is a power of two
};

// ---------------- table conversion: f32x2 entry -> packed half2 (4 B) ------
// Entries are uniform(-1e-4,1e-4); fp16 step there ~6e-8 -> rounding error
// <=3e-8/entry. Halves gather bytes AND makes each hashed table 2 MB ->
// L2-resident per XCD during its level phase (R4: FETCH 704->184 MB).
__global__ void __launch_bounds__(BLOCK)
hashenc_conv(const float4* __restrict__ emb2, uint2* __restrict__ tab16, int n2)
{
    const int i = blockIdx.x * BLOCK + threadIdx.x;
    if (i < n2) {
        const float4 v = emb2[i];
        const __half2 a = __floats2half2_rn(v.x, v.y);
        const __half2 b = __floats2half2_rn(v.z, v.w);
        tab16[i] = make_uint2(*(const unsigned*)&a, *(const unsigned*)&b);
    }
}

// ---------------- coarse levels (0,1): table staged in LDS ------------------
// pass1 is at the L2 line-service roofline (~0.55 line-touches/cy/CU across
// all R0-R5 variants), so the only lever left is removing requests from L2.
// Levels 0/1 tables (19.6 KB / 143.7 KB fp16) fit LDS; gather from LDS costs
// zero L2 service. Chunked staging (48 KB static) keeps static-LDS size safe;
// each corner contributes in exactly one chunk (ranges partition [0,hs)).
__global__ void __launch_bounds__(BLOCK)
hashenc_coarse(const float* __restrict__ xyz,
               const unsigned* __restrict__ tab16,
               unsigned* __restrict__ ws,
               HashParams p, int np, int cblk_shift)
{
    __shared__ unsigned stab[CCHUNK];
    const int l = blockIdx.x >> cblk_shift;              // 0 or 1
    const int blk = blockIdx.x & ((1 << cblk_shift) - 1);
    const int tid = threadIdx.x;

    const unsigned hs = p.hsize[l];
    const unsigned* __restrict__ tab = tab16 + p.offs[l];
    const float scale = (float)((16u << l) - 1u);
    unsigned* __restrict__ wl = ws + (size_t)l * np;
    const int nchunks = (int)((hs + CCHUNK - 1) / CCHUNK);
    const int base = blk * (BLOCK * PPT_C);

    float acc0[PPT_C], acc1[PPT_C];
#pragma unroll
    for (int s = 0; s < PPT_C; ++s) { acc0[s] = 0.0f; acc1[s] = 0.0f; }

    for (int c = 0; c < nchunks; ++c) {
        const unsigned c0 = (unsigned)c * CCHUNK;
        const unsigned cend = (c0 + CCHUNK < hs) ? c0 + CCHUNK : hs;
        __syncthreads();                                  // prior reads done
        for (int i = tid; i < (int)(cend - c0); i += BLOCK)
            stab[i] = tab[c0 + i];
        __syncthreads();

#pragma unroll
        for (int s = 0; s < PPT_C; ++s) {
            const int pidx = base + s * BLOCK + tid;
            const float x = xyz[pidx * 3 + 0];
            const float y = xyz[pidx * 3 + 1];
            const float z = xyz[pidx * 3 + 2];
            const float px = x * scale + 0.5f;
            const float py = y * scale + 0.5f;
            const float pz = z * scale + 0.5f;
            const float gx = floorf(px), gy = floorf(py), gz = floorf(pz);
            const float fx = px - gx, fy = py - gy, fz = pz - gz;
            const unsigned ix = (unsigned)gx, iy = (unsigned)gy, iz = (unsigned)gz;
            const unsigned hy0 = iy * 2654435761u;
            const unsigned hz0 = iz * 805459861u;
            const unsigned hy1 = hy0 + 2654435761u;
            const unsigned hz1 = hz0 + 805459861u;
            const unsigned hyz[4] = { hy0 ^ hz0, hy1 ^ hz0, hy0 ^ hz1, hy1 ^ hz1 };
            const float wxv[2] = {1.0f - fx, fx};
            const float wyv[2] = {1.0f - fy, fy};
            const float wzv[2] = {1.0f - fz, fz};
            float o0 = acc0[s], o1 = acc1[s];
#pragma unroll
            for (int q = 0; q < 4; ++q) {
                const float wq = wyv[q & 1] * wzv[q >> 1];
#pragma unroll
                for (int cx = 0; cx < 2; ++cx) {
                    const unsigned idx = ((ix + (unsigned)cx) ^ hyz[q]) % hs;
                    if (idx >= c0 && idx < cend) {
                        const unsigned u = stab[idx - c0];
                        const float2 e = __half22float2(*reinterpret_cast<const __half2*>(&u));
                        const float w = wxv[cx] * wq;
                        o0 = fmaf(w, e.x, o0);
                        o1 = fmaf(w, e.y, o1);
                    }
                }
            }
            acc0[s] = o0; acc1[s] = o1;
        }
    }

#pragma unroll
    for (int s = 0; s < PPT_C; ++s) {
        const int pidx = base + s * BLOCK + tid;
        const __half2 ph = __floats2half2_rn(acc0[s], acc1[s]);
        wl[pidx] = *(const unsigned*)&ph;                 // 4 B coalesced store
    }
}

// ---------------- pass 1 (fp16 table): levels 2..15, issue-all-then-consume -
// Level-major dispatch: each XCD's L2 holds one 2 MB table at a time.
__global__ void __launch_bounds__(BLOCK)
hashenc_pass1_h(const float* __restrict__ xyz,
                const unsigned* __restrict__ tab16,
                unsigned* __restrict__ ws,
                HashParams p, int np, int bpl_shift)
{
    const int l = NCOARSE + (blockIdx.x >> bpl_shift);
    const int chunk = blockIdx.x & ((1 << bpl_shift) - 1);
    const int tid = threadIdx.x;

    __shared__ float sxyz[BLOCK * PPT1 * 3];  // 12 KB staged coords
    {
        const float4* __restrict__ src =
            (const float4*)(xyz + (size_t)chunk * (BLOCK * PPT1) * 3);
        float4* __restrict__ dst = (float4*)sxyz;
#pragma unroll
        for (int i = tid; i < (BLOCK * PPT1 * 3) / 4; i += BLOCK)
            dst[i] = src[i];
    }
    __syncthreads();

    const unsigned hs = p.hsize[l];
    const unsigned* __restrict__ tab = tab16 + p.offs[l];
    const float scale = (float)((16u << l) - 1u);
    const bool is_pow2 = (p.pow2_bits >> l) & 1u;
    unsigned* __restrict__ wl = ws + (size_t)l * np;

    unsigned raw[PPT1][8];    // all compile-time indexed
    unsigned selba[PPT1];     // bit q: swap r0/r1 for corner-pair q
    float fxa[PPT1], fya[PPT1], fza[PPT1];

    // ---- phase A: indices + issue all gathers ----
#pragma unroll
    for (int s = 0; s < PPT1; ++s) {
        const int lp = s * BLOCK + tid;
        const float x = sxyz[lp * 3 + 0];
        const float y = sxyz[lp * 3 + 1];
        const float z = sxyz[lp * 3 + 2];
        const float px = x * scale + 0.5f;
        const float py = y * scale + 0.5f;
        const float pz = z * scale + 0.5f;
        const float gx = floorf(px), gy = floorf(py), gz = floorf(pz);
        fxa[s] = px - gx; fya[s] = py - gy; fza[s] = pz - gz;
        const unsigned ix = (unsigned)gx, iy = (unsigned)gy, iz = (unsigned)gz;

        const unsigned hy0 = iy * 2654435761u;
        const unsigned hz0 = iz * 805459861u;
        const unsigned hy1 = hy0 + 2654435761u;
        const unsigned hz1 = hz0 + 805459861u;
        const unsigned hyz[4] = { hy0 ^ hz0, hy1 ^ hz0, hy0 ^ hz1, hy1 ^ hz1 };

        unsigned selb = 0u;
        if (is_pow2) {
            const unsigned m = hs - 1u;
            if (!(ix & 1u)) {
                // even ix: x-corners are v0 and v0^1 -> one 8 B dwordx2 pair
#pragma unroll
                for (int q = 0; q < 4; ++q) {
                    const unsigned v0 = (ix ^ hyz[q]) & m;
                    const uint2 pr = *reinterpret_cast<const uint2*>(tab + (v0 & ~1u));
                    raw[s][2 * q]     = pr.x;   // entry v0&~1
                    raw[s][2 * q + 1] = pr.y;   // entry v0|1
                    selb |= (v0 & 1u) << q;     // v0 odd -> corner cx=0 is pr.y
                }
            } else {
#pragma unroll
                for (int q = 0; q < 4; ++q) {
                    raw[s][2 * q]     = tab[(ix ^ hyz[q]) & m];
                    raw[s][2 * q + 1] = tab[((ix + 1u) ^ hyz[q]) & m];
                }
            }
        } else {
            // non-pow2 hashed level (level 2 only here): % path
#pragma unroll
            for (int q = 0; q < 4; ++q) {
                raw[s][2 * q]     = tab[(ix ^ hyz[q]) % hs];
                raw[s][2 * q + 1] = tab[((ix + 1u) ^ hyz[q]) % hs];
            }
        }
        selba[s] = selb;
    }

    // ---- phase B: convert + trilinear interp + packed store ----
#pragma unroll
    for (int s = 0; s < PPT1; ++s) {
        const float fx = fxa[s], fy = fya[s], fz = fza[s];
        const float wxv[2] = {1.0f - fx, fx};
        const float wyv[2] = {1.0f - fy, fy};
        const float wzv[2] = {1.0f - fz, fz};
        const unsigned selb = selba[s];
        float o0 = 0.0f, o1 = 0.0f;
#pragma unroll
        for (int q = 0; q < 4; ++q) {
            const unsigned r0 = raw[s][2 * q], r1 = raw[s][2 * q + 1];
            const bool sw = (selb >> q) & 1u;
            const unsigned ua = sw ? r1 : r0;   // corner cx=0
            const unsigned ub = sw ? r0 : r1;   // corner cx=1
            const float2 ea = __half22float2(*reinterpret_cast<const __half2*>(&ua));
            const float2 eb = __half22float2(*reinterpret_cast<const __half2*>(&ub));
            const float wq = wyv[q & 1] * wzv[q >> 1];
            const float w0 = wxv[0] * wq, w1 = wxv[1] * wq;
            o0 = fmaf(w0, ea.x, o0); o1 = fmaf(w0, ea.y, o1);
            o0 = fmaf(w1, eb.x, o0); o1 = fmaf(w1, eb.y, o1);
        }
        const int pidx = chunk * (BLOCK * PPT1) + s * BLOCK + tid;
        const __half2 ph = __floats2half2_rn(o0, o1);
        wl[pidx] = *(const unsigned*)&ph;   // 4 B coalesced store
    }
}

// ---------------- pass 2: LDS transpose, half2 ws -> f32 out ---------------
__global__ void __launch_bounds__(BLOCK)
hashenc_pass2_h(const unsigned* __restrict__ ws, float* __restrict__ out, int np)
{
    __shared__ float lds[BLOCK * 33];
    const int tid = threadIdx.x;
    const int p0 = blockIdx.x * BLOCK;

#pragma unroll
    for (int l = 0; l < NLEVELS; ++l) {
        const unsigned u = ws[(size_t)l * np + p0 + tid];   // coalesced 4 B/lane
        const float2 v = __half22float2(*reinterpret_cast<const __half2*>(&u));
        lds[tid * 33 + 2 * l + 0] = v.x;    // bank (tid+2l)%32: conflict-free
        lds[tid * 33 + 2 * l + 1] = v.y;
    }
    __syncthreads();
    float* __restrict__ ochunk = out + (size_t)blockIdx.x * (BLOCK * 32);
#pragma unroll
    for (int k = 0; k < 32; ++k) {
        const int flat = k * BLOCK + tid;
        const float v = lds[(flat >> 5) * 33 + (flat & 31)];
        __builtin_nontemporal_store(v, ochunk + flat);
    }
}

// ---------------- tier 2: f32 two-pass --------------------------------------
__global__ void __launch_bounds__(BLOCK)
hashenc_pass1_f32(const float* __restrict__ xyz,
                  const float* __restrict__ emb,
                  float2* __restrict__ ws,
                  HashParams p, int np, int bpl_shift)
{
    const int l = blockIdx.x >> bpl_shift;
    const int chunk = blockIdx.x & ((1 << bpl_shift) - 1);
    const int tid = threadIdx.x;

    __shared__ float sxyz[BLOCK * PPT * 3];
    {
        const float4* __restrict__ src =
            (const float4*)(xyz + (size_t)chunk * (BLOCK * PPT) * 3);
        float4* __restrict__ dst = (float4*)sxyz;
#pragma unroll
        for (int i = tid; i < (BLOCK * PPT * 3) / 4; i += BLOCK)
            dst[i] = src[i];
    }
    __syncthreads();

    const unsigned hs = p.hsize[l];
    const float2* __restrict__ tab = (const float2*)emb + p.offs[l];
    const float scale = (float)((16u << l) - 1u);
    const bool do_hash = (p.hash_bits >> l) & 1u;
    const bool is_pow2 = (p.pow2_bits >> l) & 1u;
    float2* __restrict__ wl = ws + (size_t)l * np;

#pragma unroll
    for (int s = 0; s < PPT; ++s) {
        const int lp = s * BLOCK + tid;
        const int pidx = chunk * (BLOCK * PPT) + lp;
        const float x = sxyz[lp * 3 + 0];
        const float y = sxyz[lp * 3 + 1];
        const float z = sxyz[lp * 3 + 2];
        const float px = x * scale + 0.5f;
        const float py = y * scale + 0.5f;
        const float pz = z * scale + 0.5f;
        const float gx = floorf(px), gy = floorf(py), gz = floorf(pz);
        const float fx = px - gx, fy = py - gy, fz = pz - gz;
        const unsigned ix = (unsigned)gx, iy = (unsigned)gy, iz = (unsigned)gz;
        const float wxv[2] = {1.0f - fx, fx};
        const float wyv[2] = {1.0f - fy, fy};
        const float wzv[2] = {1.0f - fz, fz};
        float o0 = 0.0f, o1 = 0.0f;
        unsigned idx[8];
        if (do_hash) {
            const unsigned hy0 = iy * 2654435761u;
            const unsigned hz0 = iz * 805459861u;
            const unsigned hy1 = hy0 + 2654435761u;
            const unsigned hz1 = hz0 + 805459861u;
            if (is_pow2) {
                const unsigned m = hs - 1u;
#pragma unroll
                for (int c = 0; c < 8; ++c)
                    idx[c] = ((ix + (c & 1)) ^ ((c & 2) ? hy1 : hy0) ^ ((c & 4) ? hz1 : hz0)) & m;
            } else {
#pragma unroll
                for (int c = 0; c < 8; ++c)
                    idx[c] = ((ix + (c & 1)) ^ ((c & 2) ? hy1 : hy0) ^ ((c & 4) ? hz1 : hz0)) % hs;
            }
        } else {
            const unsigned stride = (16u << l) + 1u;
#pragma unroll
            for (int c = 0; c < 8; ++c) {
                const unsigned lin = (ix + (c & 1))
                                   + (iy + ((c >> 1) & 1)) * stride
                                   + (iz + ((c >> 2) & 1)) * stride * stride;
                idx[c] = lin % hs;
            }
        }
        float2 e[8];
#pragma unroll
        for (int c = 0; c < 8; ++c) e[c] = tab[idx[c]];
#pragma unroll
        for (int c = 0; c < 8; ++c) {
            const float w = wxv[c & 1] * wyv[(c >> 1) & 1] * wzv[(c >> 2) & 1];
            o0 = fmaf(w, e[c].x, o0);
            o1 = fmaf(w, e[c].y, o1);
        }
        wl[pidx] = make_float2(o0, o1);
    }
}

__global__ void __launch_bounds__(BLOCK)
hashenc_pass2(const float2* __restrict__ ws, float* __restrict__ out, int np)
{
    __shared__ float lds[BLOCK * 33];
    const int tid = threadIdx.x;
    const int p0 = blockIdx.x * BLOCK;

#pragma unroll
    for (int l = 0; l < NLEVELS; ++l) {
        const float2 v = ws[(size_t)l * np + p0 + tid];
        lds[tid * 33 + 2 * l + 0] = v.x;
        lds[tid * 33 + 2 * l + 1] = v.y;
    }
    __syncthreads();
    float* __restrict__ ochunk = out + (size_t)blockIdx.x * (BLOCK * 32);
#pragma unroll
    for (int k = 0; k < 32; ++k) {
        const int flat = k * BLOCK + tid;
        const float v = lds[(flat >> 5) * 33 + (flat & 31)];
        __builtin_nontemporal_store(v, ochunk + flat);
    }
}

// ---------------- tier 3: single-pass fallback ------------------------------
__global__ void __launch_bounds__(BLOCK)
hashenc_fwd(const float* __restrict__ xyz,
            const float* __restrict__ emb,
            float* __restrict__ out,
            HashParams p)
{
    const int tid = threadIdx.x;
    const long b = (long)blockIdx.x * BLOCK + tid;
    __shared__ float lds[BLOCK * 33];

    const float x = xyz[b * 3 + 0];
    const float y = xyz[b * 3 + 1];
    const float z = xyz[b * 3 + 2];

#pragma unroll
    for (int l = 0; l < NLEVELS; ++l) {
        const float scale = (float)((16u << l) - 1u);
        const float px = x * scale + 0.5f;
        const float py = y * scale + 0.5f;
        const float pz = z * scale + 0.5f;
        const float gx = floorf(px), gy = floorf(py), gz = floorf(pz);
        const float fx = px - gx, fy = py - gy, fz = pz - gz;
        const unsigned ix = (unsigned)gx, iy = (unsigned)gy, iz = (unsigned)gz;
        const unsigned hs = p.hsize[l];
        const float2* __restrict__ tab = (const float2*)emb + p.offs[l];

        unsigned idx[8];
        if ((p.hash_bits >> l) & 1u) {
            const unsigned hy0 = iy * 2654435761u;
            const unsigned hz0 = iz * 805459861u;
            const unsigned hy1 = hy0 + 2654435761u;
            const unsigned hz1 = hz0 + 805459861u;
            if ((p.pow2_bits >> l) & 1u) {
                const unsigned m = hs - 1u;
#pragma unroll
                for (int c = 0; c < 8; ++c)
                    idx[c] = ((ix + (c & 1)) ^ ((c & 2) ? hy1 : hy0) ^ ((c & 4) ? hz1 : hz0)) & m;
            } else {
#pragma unroll
                for (int c = 0; c < 8; ++c)
                    idx[c] = ((ix + (c & 1)) ^ ((c & 2) ? hy1 : hy0) ^ ((c & 4) ? hz1 : hz0)) % hs;
            }
        } else {
            const unsigned stride = (16u << l) + 1u;
#pragma unroll
            for (int c = 0; c < 8; ++c) {
                const unsigned lin = (ix + (c & 1))
                                   + (iy + ((c >> 1) & 1)) * stride
                                   + (iz + ((c >> 2) & 1)) * stride * stride;
                idx[c] = lin % hs;
            }
        }

        float2 e[8];
#pragma unroll
        for (int c = 0; c < 8; ++c) e[c] = tab[idx[c]];

        const float wx[2] = {1.0f - fx, fx};
        const float wy[2] = {1.0f - fy, fy};
        const float wz[2] = {1.0f - fz, fz};
        float o0 = 0.0f, o1 = 0.0f;
#pragma unroll
        for (int c = 0; c < 8; ++c) {
            const float w = wx[c & 1] * wy[(c >> 1) & 1] * wz[(c >> 2) & 1];
            o0 = fmaf(w, e[c].x, o0);
            o1 = fmaf(w, e[c].y, o1);
        }
        lds[tid * 33 + l * 2 + 0] = o0;
        lds[tid * 33 + l * 2 + 1] = o1;
    }

    __syncthreads();
    float* __restrict__ ochunk = out + (long)blockIdx.x * (BLOCK * 32);
#pragma unroll
    for (int k = 0; k < 32; ++k) {
        const int flat = k * BLOCK + tid;
        const float v = lds[(flat >> 5) * 33 + (flat & 31)];
        __builtin_nontemporal_store(v, ochunk + flat);
    }
}

extern "C" void kernel_launch(void* const* d_in, const int* in_sizes, int n_in,
                              void* d_out, int out_size, void* d_ws, size_t ws_size,
                              hipStream_t stream) {
    const float* xyz = (const float*)d_in[0];
    const float* emb = (const float*)d_in[1];
    float* out = (float*)d_out;
    const int B = in_sizes[0] / 3;

    // Reproduce HashEncoder.__init__ offset arithmetic exactly.
    HashParams p;
    p.offs[0] = 0;
    unsigned hash_bits = 0, pow2_bits = 0;
    long off = 0;
    for (int i = 0; i < NLEVELS; ++i) {
        const long res = 16L << i;
        const long dense = (res + 1) * (res + 1) * (res + 1);
        long t = dense < (1L << 19) ? dense : (1L << 19);
        t = (t / 8) * 8;
        p.hsize[i] = (unsigned)t;
        off += t;
        p.offs[i + 1] = (unsigned)off;
        if (dense > t) hash_bits |= (1u << i);   // true for ALL levels here
        if ((t & (t - 1)) == 0) pow2_bits |= (1u << i);
    }
    p.hash_bits = hash_bits;
    p.pow2_bits = pow2_bits;

    const long nent = off;                               // total table entries
    const size_t need_ws16 = (size_t)B * NLEVELS * 4;    // half2 ws (64 MB)
    const size_t need_h = need_ws16 + (size_t)nent * 4;  // + fp16 table (92.6 MB)
    const size_t need_f32 = (size_t)B * NLEVELS * sizeof(float2);
    const bool shape1_ok = (B % (BLOCK * PPT1)) == 0 && (B % (BLOCK * PPT_C)) == 0
                        && (B % BLOCK) == 0;
    const bool shape2_ok = (B % (BLOCK * PPT)) == 0 && (B % BLOCK) == 0;
    const bool all_hashed = (hash_bits == ((1u << NLEVELS) - 1u));
    // coarse LDS kernel needs lv0/lv1 tables <= 13 chunks worth; true here
    const bool coarse_ok = p.hsize[0] <= 4u * CCHUNK && p.hsize[1] <= 4u * CCHUNK;

    if (shape1_ok && all_hashed && coarse_ok && ws_size >= need_h) {
        // tier 1: fp16 table + half2 ws; coarse levels via LDS-staged tables
        unsigned* tab16 = (unsigned*)((char*)d_ws + need_ws16);
        const int n2 = (int)(nent / 2);
        hashenc_conv<<<dim3((n2 + BLOCK - 1) / BLOCK), dim3(BLOCK), 0, stream>>>(
            (const float4*)emb, (uint2*)tab16, n2);

        int cblk_shift = 0;
        while ((1 << cblk_shift) * (BLOCK * PPT_C) < B) ++cblk_shift;  // B is pow2
        hashenc_coarse<<<dim3(NCOARSE << cblk_shift), dim3(BLOCK), 0, stream>>>(
            xyz, tab16, (unsigned*)d_ws, p, B, cblk_shift);

        int bpl_shift = 0;
        while ((1 << bpl_shift) * (BLOCK * PPT1) < B) ++bpl_shift;
        hashenc_pass1_h<<<dim3((NLEVELS - NCOARSE) << bpl_shift), dim3(BLOCK), 0, stream>>>(
            xyz, tab16, (unsigned*)d_ws, p, B, bpl_shift);

        hashenc_pass2_h<<<dim3(B / BLOCK), dim3(BLOCK), 0, stream>>>(
            (const unsigned*)d_ws, out, B);
    } else if (shape2_ok && ws_size >= need_f32) {
        // tier 2: f32 two-pass
        int bpl_shift = 0;
        while ((1 << bpl_shift) * (BLOCK * PPT) < B) ++bpl_shift;
        const int bpl = 1 << bpl_shift;
        hashenc_pass1_f32<<<dim3(NLEVELS * bpl), dim3(BLOCK), 0, stream>>>(
            xyz, emb, (float2*)d_ws, p, B, bpl_shift);
        hashenc_pass2<<<dim3(B / BLOCK), dim3(BLOCK), 0, stream>>>(
            (const float2*)d_ws, out, B);
    } else {
        // tier 3: single-pass fallback
        hashenc_fwd<<<dim3(B / BLOCK), dim3(BLOCK), 0, stream>>>(xyz, emb, out, p);
    }
}

// Round 7
// 502.434 us; speedup vs baseline: 1.0015x; 1.0015x over previous
//
#include <hip/hip_runtime.h>
#include <hip/hip_fp16.h>

#define NLEVELS 16
#define BLOCK 256
#define PPT1 4       // points per thread, fp16 main pass-1
#define PPT 2        // points per thread, f32 fallback pass-1
#define CCHUNK 12288 // coarse LDS chunk entries (48 KB)
#define PPT_C 4      // coarse points per thread
#define NCOARSE 2    // levels 0..NCOARSE-1 handled by the LDS-table kernel

struct HashParams {
    unsigned offs[NLEVELS + 1];  // per-level table offsets (entries)
    unsigned hsize[NLEVELS];     // per-level table size (entries)
    unsigned hash_bits;          // bit l set -> hash path for level l (all, this config)
    unsigned pow2_bits;          // bit l set -> hsize[l] is a power of two
};

// ---------------- table conversion: f32x2 entry -> packed half2 (4 B) ------
// Entries are uniform(-1e-4,1e-4); fp16 step there ~6e-8 -> rounding error
// <=3e-8/entry. Halves gather bytes AND makes each hashed table 2 MB ->
// L2-resident per XCD during its level phase (R4: FETCH 704->184 MB).
__global__ void __launch_bounds__(BLOCK)
hashenc_conv(const float4* __restrict__ emb2, uint2* __restrict__ tab16, int n2)
{
    const int i = blockIdx.x * BLOCK + threadIdx.x;
    if (i < n2) {
        const float4 v = emb2[i];
        const __half2 a = __floats2half2_rn(v.x, v.y);
        const __half2 b = __floats2half2_rn(v.z, v.w);
        tab16[i] = make_uint2(*(const unsigned*)&a, *(const unsigned*)&b);
    }
}

// ---------------- coarse levels (0,1): table staged in LDS ------------------
// pass1 sits at the L2 line-service roofline (~0.55 line-touches/cy/CU,
// invariant across R0-R5), so these levels gather from LDS instead (zero L2
// service). v2 (R6 post-mortem): idx[8] and w[8] are computed ONCE into
// registers (8 runtime-% per point, not 24); the chunk loop is only
// {range-test, predicated LDS gather, fma}. Staging is uint4-wide.
__global__ void __launch_bounds__(BLOCK)
hashenc_coarse(const float* __restrict__ xyz,
               const unsigned* __restrict__ tab16,
               unsigned* __restrict__ ws,
               HashParams p, int np, int cblk_shift)
{
    __shared__ uint4 stab4[CCHUNK / 4];
    unsigned* stab = (unsigned*)stab4;
    const int l = blockIdx.x >> cblk_shift;              // 0 or 1
    const int blk = blockIdx.x & ((1 << cblk_shift) - 1);
    const int tid = threadIdx.x;

    const unsigned hs = p.hsize[l];
    const unsigned* __restrict__ tab = tab16 + p.offs[l];
    const float scale = (float)((16u << l) - 1u);
    unsigned* __restrict__ wl = ws + (size_t)l * np;
    const int nchunks = (int)((hs + CCHUNK - 1) / CCHUNK);
    const int base = blk * (BLOCK * PPT_C);

    unsigned idxa[PPT_C][8];   // all compile-time indexed (rule #20)
    float wa[PPT_C][8];
    float acc0[PPT_C], acc1[PPT_C];

    // ---- once per point: hash indices + trilinear weights ----
#pragma unroll
    for (int s = 0; s < PPT_C; ++s) {
        acc0[s] = 0.0f; acc1[s] = 0.0f;
        const int pidx = base + s * BLOCK + tid;
        const float x = xyz[pidx * 3 + 0];
        const float y = xyz[pidx * 3 + 1];
        const float z = xyz[pidx * 3 + 2];
        const float px = x * scale + 0.5f;
        const float py = y * scale + 0.5f;
        const float pz = z * scale + 0.5f;
        const float gx = floorf(px), gy = floorf(py), gz = floorf(pz);
        const float fx = px - gx, fy = py - gy, fz = pz - gz;
        const unsigned ix = (unsigned)gx, iy = (unsigned)gy, iz = (unsigned)gz;
        const unsigned hy0 = iy * 2654435761u;
        const unsigned hz0 = iz * 805459861u;
        const unsigned hy1 = hy0 + 2654435761u;
        const unsigned hz1 = hz0 + 805459861u;
        const unsigned hyz[4] = { hy0 ^ hz0, hy1 ^ hz0, hy0 ^ hz1, hy1 ^ hz1 };
        const float wxv[2] = {1.0f - fx, fx};
        const float wyv[2] = {1.0f - fy, fy};
        const float wzv[2] = {1.0f - fz, fz};
#pragma unroll
        for (int c = 0; c < 8; ++c) {            // c = cx | cy<<1 | cz<<2
            idxa[s][c] = ((ix + (c & 1)) ^ hyz[c >> 1]) % hs;
            wa[s][c] = wxv[c & 1] * wyv[(c >> 1) & 1] * wzv[c >> 2];
        }
    }

    // ---- chunk loop: stage + predicated gather-accumulate ----
    for (int c = 0; c < nchunks; ++c) {
        const unsigned c0 = (unsigned)c * CCHUNK;
        const unsigned cnt = (hs - c0 < CCHUNK) ? hs - c0 : CCHUNK;
        __syncthreads();                          // prior chunk's reads done
        {
            const uint4* __restrict__ src = (const uint4*)(tab + c0);
            const int n4 = (int)(cnt >> 2);       // all level sizes %4 == 0
            for (int i = tid; i < n4; i += BLOCK)
                stab4[i] = src[i];
        }
        __syncthreads();
#pragma unroll
        for (int s = 0; s < PPT_C; ++s) {
#pragma unroll
            for (int k = 0; k < 8; ++k) {
                const unsigned rel = idxa[s][k] - c0;   // wraps if below c0
                if (rel < cnt) {
                    const unsigned u = stab[rel];
                    const float2 e = __half22float2(*reinterpret_cast<const __half2*>(&u));
                    acc0[s] = fmaf(wa[s][k], e.x, acc0[s]);
                    acc1[s] = fmaf(wa[s][k], e.y, acc1[s]);
                }
            }
        }
    }

#pragma unroll
    for (int s = 0; s < PPT_C; ++s) {
        const int pidx = base + s * BLOCK + tid;
        const __half2 ph = __floats2half2_rn(acc0[s], acc1[s]);
        wl[pidx] = *(const unsigned*)&ph;         // 4 B coalesced store
    }
}

// ---------------- pass 1 (fp16 table): levels 2..15, issue-all-then-consume -
// Level-major dispatch: each XCD's L2 holds one 2 MB table at a time.
__global__ void __launch_bounds__(BLOCK)
hashenc_pass1_h(const float* __restrict__ xyz,
                const unsigned* __restrict__ tab16,
                unsigned* __restrict__ ws,
                HashParams p, int np, int bpl_shift)
{
    const int l = NCOARSE + (blockIdx.x >> bpl_shift);
    const int chunk = blockIdx.x & ((1 << bpl_shift) - 1);
    const int tid = threadIdx.x;

    __shared__ float sxyz[BLOCK * PPT1 * 3];  // 12 KB staged coords
    {
        const float4* __restrict__ src =
            (const float4*)(xyz + (size_t)chunk * (BLOCK * PPT1) * 3);
        float4* __restrict__ dst = (float4*)sxyz;
#pragma unroll
        for (int i = tid; i < (BLOCK * PPT1 * 3) / 4; i += BLOCK)
            dst[i] = src[i];
    }
    __syncthreads();

    const unsigned hs = p.hsize[l];
    const unsigned* __restrict__ tab = tab16 + p.offs[l];
    const float scale = (float)((16u << l) - 1u);
    const bool is_pow2 = (p.pow2_bits >> l) & 1u;
    unsigned* __restrict__ wl = ws + (size_t)l * np;

    unsigned raw[PPT1][8];    // all compile-time indexed
    unsigned selba[PPT1];     // bit q: swap r0/r1 for corner-pair q
    float fxa[PPT1], fya[PPT1], fza[PPT1];

    // ---- phase A: indices + issue all gathers ----
#pragma unroll
    for (int s = 0; s < PPT1; ++s) {
        const int lp = s * BLOCK + tid;
        const float x = sxyz[lp * 3 + 0];
        const float y = sxyz[lp * 3 + 1];
        const float z = sxyz[lp * 3 + 2];
        const float px = x * scale + 0.5f;
        const float py = y * scale + 0.5f;
        const float pz = z * scale + 0.5f;
        const float gx = floorf(px), gy = floorf(py), gz = floorf(pz);
        fxa[s] = px - gx; fya[s] = py - gy; fza[s] = pz - gz;
        const unsigned ix = (unsigned)gx, iy = (unsigned)gy, iz = (unsigned)gz;

        const unsigned hy0 = iy * 2654435761u;
        const unsigned hz0 = iz * 805459861u;
        const unsigned hy1 = hy0 + 2654435761u;
        const unsigned hz1 = hz0 + 805459861u;
        const unsigned hyz[4] = { hy0 ^ hz0, hy1 ^ hz0, hy0 ^ hz1, hy1 ^ hz1 };

        unsigned selb = 0u;
        if (is_pow2) {
            const unsigned m = hs - 1u;
            if (!(ix & 1u)) {
                // even ix: x-corners are v0 and v0^1 -> one 8 B dwordx2 pair
#pragma unroll
                for (int q = 0; q < 4; ++q) {
                    const unsigned v0 = (ix ^ hyz[q]) & m;
                    const uint2 pr = *reinterpret_cast<const uint2*>(tab + (v0 & ~1u));
                    raw[s][2 * q]     = pr.x;   // entry v0&~1
                    raw[s][2 * q + 1] = pr.y;   // entry v0|1
                    selb |= (v0 & 1u) << q;     // v0 odd -> corner cx=0 is pr.y
                }
            } else {
#pragma unroll
                for (int q = 0; q < 4; ++q) {
                    raw[s][2 * q]     = tab[(ix ^ hyz[q]) & m];
                    raw[s][2 * q + 1] = tab[((ix + 1u) ^ hyz[q]) & m];
                }
            }
        } else {
            // non-pow2 hashed level (level 2 only here): % path
#pragma unroll
            for (int q = 0; q < 4; ++q) {
                raw[s][2 * q]     = tab[(ix ^ hyz[q]) % hs];
                raw[s][2 * q + 1] = tab[((ix + 1u) ^ hyz[q]) % hs];
            }
        }
        selba[s] = selb;
    }

    // ---- phase B: convert + trilinear interp + packed store ----
#pragma unroll
    for (int s = 0; s < PPT1; ++s) {
        const float fx = fxa[s], fy = fya[s], fz = fza[s];
        const float wxv[2] = {1.0f - fx, fx};
        const float wyv[2] = {1.0f - fy, fy};
        const float wzv[2] = {1.0f - fz, fz};
        const unsigned selb = selba[s];
        float o0 = 0.0f, o1 = 0.0f;
#pragma unroll
        for (int q = 0; q < 4; ++q) {
            const unsigned r0 = raw[s][2 * q], r1 = raw[s][2 * q + 1];
            const bool sw = (selb >> q) & 1u;
            const unsigned ua = sw ? r1 : r0;   // corner cx=0
            const unsigned ub = sw ? r0 : r1;   // corner cx=1
            const float2 ea = __half22float2(*reinterpret_cast<const __half2*>(&ua));
            const float2 eb = __half22float2(*reinterpret_cast<const __half2*>(&ub));
            const float wq = wyv[q & 1] * wzv[q >> 1];
            const float w0 = wxv[0] * wq, w1 = wxv[1] * wq;
            o0 = fmaf(w0, ea.x, o0); o1 = fmaf(w0, ea.y, o1);
            o0 = fmaf(w1, eb.x, o0); o1 = fmaf(w1, eb.y, o1);
        }
        const int pidx = chunk * (BLOCK * PPT1) + s * BLOCK + tid;
        const __half2 ph = __floats2half2_rn(o0, o1);
        wl[pidx] = *(const unsigned*)&ph;   // 4 B coalesced store
    }
}

// ---------------- pass 2: LDS transpose, half2 ws -> f32 out ---------------
__global__ void __launch_bounds__(BLOCK)
hashenc_pass2_h(const unsigned* __restrict__ ws, float* __restrict__ out, int np)
{
    __shared__ float lds[BLOCK * 33];
    const int tid = threadIdx.x;
    const int p0 = blockIdx.x * BLOCK;

#pragma unroll
    for (int l = 0; l < NLEVELS; ++l) {
        const unsigned u = ws[(size_t)l * np + p0 + tid];   // coalesced 4 B/lane
        const float2 v = __half22float2(*reinterpret_cast<const __half2*>(&u));
        lds[tid * 33 + 2 * l + 0] = v.x;    // bank (tid+2l)%32: conflict-free
        lds[tid * 33 + 2 * l + 1] = v.y;
    }
    __syncthreads();
    float* __restrict__ ochunk = out + (size_t)blockIdx.x * (BLOCK * 32);
#pragma unroll
    for (int k = 0; k < 32; ++k) {
        const int flat = k * BLOCK + tid;
        const float v = lds[(flat >> 5) * 33 + (flat & 31)];
        __builtin_nontemporal_store(v, ochunk + flat);
    }
}

// ---------------- tier 2: f32 two-pass --------------------------------------
__global__ void __launch_bounds__(BLOCK)
hashenc_pass1_f32(const float* __restrict__ xyz,
                  const float* __restrict__ emb,
                  float2* __restrict__ ws,
                  HashParams p, int np, int bpl_shift)
{
    const int l = blockIdx.x >> bpl_shift;
    const int chunk = blockIdx.x & ((1 << bpl_shift) - 1);
    const int tid = threadIdx.x;

    __shared__ float sxyz[BLOCK * PPT * 3];
    {
        const float4* __restrict__ src =
            (const float4*)(xyz + (size_t)chunk * (BLOCK * PPT) * 3);
        float4* __restrict__ dst = (float4*)sxyz;
#pragma unroll
        for (int i = tid; i < (BLOCK * PPT * 3) / 4; i += BLOCK)
            dst[i] = src[i];
    }
    __syncthreads();

    const unsigned hs = p.hsize[l];
    const float2* __restrict__ tab = (const float2*)emb + p.offs[l];
    const float scale = (float)((16u << l) - 1u);
    const bool do_hash = (p.hash_bits >> l) & 1u;
    const bool is_pow2 = (p.pow2_bits >> l) & 1u;
    float2* __restrict__ wl = ws + (size_t)l * np;

#pragma unroll
    for (int s = 0; s < PPT; ++s) {
        const int lp = s * BLOCK + tid;
        const int pidx = chunk * (BLOCK * PPT) + lp;
        const float x = sxyz[lp * 3 + 0];
        const float y = sxyz[lp * 3 + 1];
        const float z = sxyz[lp * 3 + 2];
        const float px = x * scale + 0.5f;
        const float py = y * scale + 0.5f;
        const float pz = z * scale + 0.5f;
        const float gx = floorf(px), gy = floorf(py), gz = floorf(pz);
        const float fx = px - gx, fy = py - gy, fz = pz - gz;
        const unsigned ix = (unsigned)gx, iy = (unsigned)gy, iz = (unsigned)gz;
        const float wxv[2] = {1.0f - fx, fx};
        const float wyv[2] = {1.0f - fy, fy};
        const float wzv[2] = {1.0f - fz, fz};
        float o0 = 0.0f, o1 = 0.0f;
        unsigned idx[8];
        if (do_hash) {
            const unsigned hy0 = iy * 2654435761u;
            const unsigned hz0 = iz * 805459861u;
            const unsigned hy1 = hy0 + 2654435761u;
            const unsigned hz1 = hz0 + 805459861u;
            if (is_pow2) {
                const unsigned m = hs - 1u;
#pragma unroll
                for (int c = 0; c < 8; ++c)
                    idx[c] = ((ix + (c & 1)) ^ ((c & 2) ? hy1 : hy0) ^ ((c & 4) ? hz1 : hz0)) & m;
            } else {
#pragma unroll
                for (int c = 0; c < 8; ++c)
                    idx[c] = ((ix + (c & 1)) ^ ((c & 2) ? hy1 : hy0) ^ ((c & 4) ? hz1 : hz0)) % hs;
            }
        } else {
            const unsigned stride = (16u << l) + 1u;
#pragma unroll
            for (int c = 0; c < 8; ++c) {
                const unsigned lin = (ix + (c & 1))
                                   + (iy + ((c >> 1) & 1)) * stride
                                   + (iz + ((c >> 2) & 1)) * stride * stride;
                idx[c] = lin % hs;
            }
        }
        float2 e[8];
#pragma unroll
        for (int c = 0; c < 8; ++c) e[c] = tab[idx[c]];
#pragma unroll
        for (int c = 0; c < 8; ++c) {
            const float w = wxv[c & 1] * wyv[(c >> 1) & 1] * wzv[(c >> 2) & 1];
            o0 = fmaf(w, e[c].x, o0);
            o1 = fmaf(w, e[c].y, o1);
        }
        wl[pidx] = make_float2(o0, o1);
    }
}

__global__ void __launch_bounds__(BLOCK)
hashenc_pass2(const float2* __restrict__ ws, float* __restrict__ out, int np)
{
    __shared__ float lds[BLOCK * 33];
    const int tid = threadIdx.x;
    const int p0 = blockIdx.x * BLOCK;

#pragma unroll
    for (int l = 0; l < NLEVELS; ++l) {
        const float2 v = ws[(size_t)l * np + p0 + tid];
        lds[tid * 33 + 2 * l + 0] = v.x;
        lds[tid * 33 + 2 * l + 1] = v.y;
    }
    __syncthreads();
    float* __restrict__ ochunk = out + (size_t)blockIdx.x * (BLOCK * 32);
#pragma unroll
    for (int k = 0; k < 32; ++k) {
        const int flat = k * BLOCK + tid;
        const float v = lds[(flat >> 5) * 33 + (flat & 31)];
        __builtin_nontemporal_store(v, ochunk + flat);
    }
}

// ---------------- tier 3: single-pass fallback ------------------------------
__global__ void __launch_bounds__(BLOCK)
hashenc_fwd(const float* __restrict__ xyz,
            const float* __restrict__ emb,
            float* __restrict__ out,
            HashParams p)
{
    const int tid = threadIdx.x;
    const long b = (long)blockIdx.x * BLOCK + tid;
    __shared__ float lds[BLOCK * 33];

    const float x = xyz[b * 3 + 0];
    const float y = xyz[b * 3 + 1];
    const float z = xyz[b * 3 + 2];

#pragma unroll
    for (int l = 0; l < NLEVELS; ++l) {
        const float scale = (float)((16u << l) - 1u);
        const float px = x * scale + 0.5f;
        const float py = y * scale + 0.5f;
        const float pz = z * scale + 0.5f;
        const float gx = floorf(px), gy = floorf(py), gz = floorf(pz);
        const float fx = px - gx, fy = py - gy, fz = pz - gz;
        const unsigned ix = (unsigned)gx, iy = (unsigned)gy, iz = (unsigned)gz;
        const unsigned hs = p.hsize[l];
        const float2* __restrict__ tab = (const float2*)emb + p.offs[l];

        unsigned idx[8];
        if ((p.hash_bits >> l) & 1u) {
            const unsigned hy0 = iy * 2654435761u;
            const unsigned hz0 = iz * 805459861u;
            const unsigned hy1 = hy0 + 2654435761u;
            const unsigned hz1 = hz0 + 805459861u;
            if ((p.pow2_bits >> l) & 1u) {
                const unsigned m = hs - 1u;
#pragma unroll
                for (int c = 0; c < 8; ++c)
                    idx[c] = ((ix + (c & 1)) ^ ((c & 2) ? hy1 : hy0) ^ ((c & 4) ? hz1 : hz0)) & m;
            } else {
#pragma unroll
                for (int c = 0; c < 8; ++c)
                    idx[c] = ((ix + (c & 1)) ^ ((c & 2) ? hy1 : hy0) ^ ((c & 4) ? hz1 : hz0)) % hs;
            }
        } else {
            const unsigned stride = (16u << l) + 1u;
#pragma unroll
            for (int c = 0; c < 8; ++c) {
                const unsigned lin = (ix + (c & 1))
                                   + (iy + ((c >> 1) & 1)) * stride
                                   + (iz + ((c >> 2) & 1)) * stride * stride;
                idx[c] = lin % hs;
            }
        }

        float2 e[8];
#pragma unroll
        for (int c = 0; c < 8; ++c) e[c] = tab[idx[c]];

        const float wx[2] = {1.0f - fx, fx};
        const float wy[2] = {1.0f - fy, fy};
        const float wz[2] = {1.0f - fz, fz};
        float o0 = 0.0f, o1 = 0.0f;
#pragma unroll
        for (int c = 0; c < 8; ++c) {
            const float w = wx[c & 1] * wy[(c >> 1) & 1] * wz[(c >> 2) & 1];
            o0 = fmaf(w, e[c].x, o0);
            o1 = fmaf(w, e[c].y, o1);
        }
        lds[tid * 33 + l * 2 + 0] = o0;
        lds[tid * 33 + l * 2 + 1] = o1;
    }

    __syncthreads();
    float* __restrict__ ochunk = out + (long)blockIdx.x * (BLOCK * 32);
#pragma unroll
    for (int k = 0; k < 32; ++k) {
        const int flat = k * BLOCK + tid;
        const float v = lds[(flat >> 5) * 33 + (flat & 31)];
        __builtin_nontemporal_store(v, ochunk + flat);
    }
}

extern "C" void kernel_launch(void* const* d_in, const int* in_sizes, int n_in,
                              void* d_out, int out_size, void* d_ws, size_t ws_size,
                              hipStream_t stream) {
    const float* xyz = (const float*)d_in[0];
    const float* emb = (const float*)d_in[1];
    float* out = (float*)d_out;
    const int B = in_sizes[0] / 3;

    // Reproduce HashEncoder.__init__ offset arithmetic exactly.
    HashParams p;
    p.offs[0] = 0;
    unsigned hash_bits = 0, pow2_bits = 0;
    long off = 0;
    for (int i = 0; i < NLEVELS; ++i) {
        const long res = 16L << i;
        const long dense = (res + 1) * (res + 1) * (res + 1);
        long t = dense < (1L << 19) ? dense : (1L << 19);
        t = (t / 8) * 8;
        p.hsize[i] = (unsigned)t;
        off += t;
        p.offs[i + 1] = (unsigned)off;
        if (dense > t) hash_bits |= (1u << i);   // true for ALL levels here
        if ((t & (t - 1)) == 0) pow2_bits |= (1u << i);
    }
    p.hash_bits = hash_bits;
    p.pow2_bits = pow2_bits;

    const long nent = off;                               // total table entries
    const size_t need_ws16 = (size_t)B * NLEVELS * 4;    // half2 ws (64 MB)
    const size_t need_h = need_ws16 + (size_t)nent * 4;  // + fp16 table (92.6 MB)
    const size_t need_f32 = (size_t)B * NLEVELS * sizeof(float2);
    const bool shape1_ok = (B % (BLOCK * PPT1)) == 0 && (B % (BLOCK * PPT_C)) == 0
                        && (B % BLOCK) == 0;
    const bool shape2_ok = (B % (BLOCK * PPT)) == 0 && (B % BLOCK) == 0;
    const bool all_hashed = (hash_bits == ((1u << NLEVELS) - 1u));
    // coarse kernel: bounded chunk count, and sizes divisible by 4 (uint4 stage)
    const bool coarse_ok = p.hsize[0] <= 4u * CCHUNK && p.hsize[1] <= 4u * CCHUNK
                        && (p.hsize[0] % 4u) == 0 && (p.hsize[1] % 4u) == 0;

    if (shape1_ok && all_hashed && coarse_ok && ws_size >= need_h) {
        // tier 1: fp16 table + half2 ws; coarse levels via LDS-staged tables
        unsigned* tab16 = (unsigned*)((char*)d_ws + need_ws16);
        const int n2 = (int)(nent / 2);
        hashenc_conv<<<dim3((n2 + BLOCK - 1) / BLOCK), dim3(BLOCK), 0, stream>>>(
            (const float4*)emb, (uint2*)tab16, n2);

        int cblk_shift = 0;
        while ((1 << cblk_shift) * (BLOCK * PPT_C) < B) ++cblk_shift;  // B is pow2
        hashenc_coarse<<<dim3(NCOARSE << cblk_shift), dim3(BLOCK), 0, stream>>>(
            xyz, tab16, (unsigned*)d_ws, p, B, cblk_shift);

        int bpl_shift = 0;
        while ((1 << bpl_shift) * (BLOCK * PPT1) < B) ++bpl_shift;
        hashenc_pass1_h<<<dim3((NLEVELS - NCOARSE) << bpl_shift), dim3(BLOCK), 0, stream>>>(
            xyz, tab16, (unsigned*)d_ws, p, B, bpl_shift);

        hashenc_pass2_h<<<dim3(B / BLOCK), dim3(BLOCK), 0, stream>>>(
            (const unsigned*)d_ws, out, B);
    } else if (shape2_ok && ws_size >= need_f32) {
        // tier 2: f32 two-pass
        int bpl_shift = 0;
        while ((1 << bpl_shift) * (BLOCK * PPT) < B) ++bpl_shift;
        const int bpl = 1 << bpl_shift;
        hashenc_pass1_f32<<<dim3(NLEVELS * bpl), dim3(BLOCK), 0, stream>>>(
            xyz, emb, (float2*)d_ws, p, B, bpl_shift);
        hashenc_pass2<<<dim3(B / BLOCK), dim3(BLOCK), 0, stream>>>(
            (const float2*)d_ws, out, B);
    } else {
        // tier 3: single-pass fallback
        hashenc_fwd<<<dim3(B / BLOCK), dim3(BLOCK), 0, stream>>>(xyz, emb, out, p);
    }
}

// Round 8
// 485.339 us; speedup vs baseline: 1.0368x; 1.0352x over previous
//
#include <hip/hip_runtime.h>
#include <hip/hip_fp16.h>

#define NLEVELS 16
#define BLOCK 256
#define PPT1 4   // points per thread, fp16 pass-1 (deep MLP)
#define PPT 2    // points per thread, f32 fallback pass-1

struct HashParams {
    unsigned offs[NLEVELS + 1];  // per-level table offsets (entries)
    unsigned hsize[NLEVELS];     // per-level table size (entries)
    unsigned hash_bits;          // bit l set -> hash path for level l (all, this config)
    unsigned pow2_bits;          // bit l set -> hsize[l] is a power of two
};

// ---------------- table conversion: f32x2 entry -> packed half2 (4 B) ------
// Entries are uniform(-1e-4,1e-4); fp16 step there is ~6e-8 -> rounding error
// <=3e-8/entry. Halves gather bytes AND halves each hashed level table to
// 2 MB -> L2-resident per XCD during its level phase (R4: FETCH 704->184 MB).
__global__ void __launch_bounds__(BLOCK)
hashenc_conv(const float4* __restrict__ emb2, uint2* __restrict__ tab16, int n2)
{
    const int i = blockIdx.x * BLOCK + threadIdx.x;
    if (i < n2) {
        const float4 v = emb2[i];
        const __half2 a = __floats2half2_rn(v.x, v.y);
        const __half2 b = __floats2half2_rn(v.z, v.w);
        tab16[i] = make_uint2(*(const unsigned*)&a, *(const unsigned*)&b);
    }
}

// ---------------- pass 1 (fp16 table): issue-all-then-consume, PPT=4 --------
// Level-major dispatch (blockIdx = level*bpl + chunk): each XCD's L2 holds one
// 2 MB fp16 table at a time; levels 0/1 are L1/L2-resident and nearly free
// (R7: splitting them into an LDS-staged kernel costs more than it saves).
// Phase A computes indices and issues ALL gathers for 4 points into registers;
// phase B converts + interpolates. pass1 is L2 request-service bound:
// ~0.55 distinct-line-touches/cy/CU, invariant across R0-R7 variants.
__global__ void __launch_bounds__(BLOCK)
hashenc_pass1_h(const float* __restrict__ xyz,
                const unsigned* __restrict__ tab16,
                unsigned* __restrict__ ws,
                HashParams p, int np, int bpl_shift)
{
    const int l = blockIdx.x >> bpl_shift;
    const int chunk = blockIdx.x & ((1 << bpl_shift) - 1);
    const int tid = threadIdx.x;

    __shared__ float sxyz[BLOCK * PPT1 * 3];  // 12 KB staged coords
    {
        const float4* __restrict__ src =
            (const float4*)(xyz + (size_t)chunk * (BLOCK * PPT1) * 3);
        float4* __restrict__ dst = (float4*)sxyz;
#pragma unroll
        for (int i = tid; i < (BLOCK * PPT1 * 3) / 4; i += BLOCK)
            dst[i] = src[i];
    }
    __syncthreads();

    const unsigned hs = p.hsize[l];
    const unsigned* __restrict__ tab = tab16 + p.offs[l];
    const float scale = (float)((16u << l) - 1u);
    const bool is_pow2 = (p.pow2_bits >> l) & 1u;
    unsigned* __restrict__ wl = ws + (size_t)l * np;

    unsigned raw[PPT1][8];    // all compile-time indexed
    unsigned selba[PPT1];     // bit q: swap r0/r1 for corner-pair q
    float fxa[PPT1], fya[PPT1], fza[PPT1];

    // ---- phase A: indices + issue all gathers ----
#pragma unroll
    for (int s = 0; s < PPT1; ++s) {
        const int lp = s * BLOCK + tid;
        const float x = sxyz[lp * 3 + 0];
        const float y = sxyz[lp * 3 + 1];
        const float z = sxyz[lp * 3 + 2];
        const float px = x * scale + 0.5f;
        const float py = y * scale + 0.5f;
        const float pz = z * scale + 0.5f;
        const float gx = floorf(px), gy = floorf(py), gz = floorf(pz);
        fxa[s] = px - gx; fya[s] = py - gy; fza[s] = pz - gz;
        const unsigned ix = (unsigned)gx, iy = (unsigned)gy, iz = (unsigned)gz;

        const unsigned hy0 = iy * 2654435761u;
        const unsigned hz0 = iz * 805459861u;
        const unsigned hy1 = hy0 + 2654435761u;
        const unsigned hz1 = hz0 + 805459861u;
        const unsigned hyz[4] = { hy0 ^ hz0, hy1 ^ hz0, hy0 ^ hz1, hy1 ^ hz1 };

        unsigned selb = 0u;
        if (is_pow2) {
            const unsigned m = hs - 1u;
            if (!(ix & 1u)) {
                // even ix: x-corners are v0 and v0^1 -> one 8 B dwordx2 pair
#pragma unroll
                for (int q = 0; q < 4; ++q) {
                    const unsigned v0 = (ix ^ hyz[q]) & m;
                    const uint2 pr = *reinterpret_cast<const uint2*>(tab + (v0 & ~1u));
                    raw[s][2 * q]     = pr.x;   // entry v0&~1
                    raw[s][2 * q + 1] = pr.y;   // entry v0|1
                    selb |= (v0 & 1u) << q;     // v0 odd -> corner cx=0 is pr.y
                }
            } else {
#pragma unroll
                for (int q = 0; q < 4; ++q) {
                    raw[s][2 * q]     = tab[(ix ^ hyz[q]) & m];
                    raw[s][2 * q + 1] = tab[((ix + 1u) ^ hyz[q]) & m];
                }
            }
        } else {
            // non-pow2 hashed levels (0-2): tables tiny & cache-hot; % is fine
#pragma unroll
            for (int q = 0; q < 4; ++q) {
                raw[s][2 * q]     = tab[(ix ^ hyz[q]) % hs];
                raw[s][2 * q + 1] = tab[((ix + 1u) ^ hyz[q]) % hs];
            }
        }
        selba[s] = selb;
    }

    // ---- phase B: convert + trilinear interp + packed store ----
#pragma unroll
    for (int s = 0; s < PPT1; ++s) {
        const float fx = fxa[s], fy = fya[s], fz = fza[s];
        const float wxv[2] = {1.0f - fx, fx};
        const float wyv[2] = {1.0f - fy, fy};
        const float wzv[2] = {1.0f - fz, fz};
        const unsigned selb = selba[s];
        float o0 = 0.0f, o1 = 0.0f;
#pragma unroll
        for (int q = 0; q < 4; ++q) {
            const unsigned r0 = raw[s][2 * q], r1 = raw[s][2 * q + 1];
            const bool sw = (selb >> q) & 1u;
            const unsigned ua = sw ? r1 : r0;   // corner cx=0
            const unsigned ub = sw ? r0 : r1;   // corner cx=1
            const float2 ea = __half22float2(*reinterpret_cast<const __half2*>(&ua));
            const float2 eb = __half22float2(*reinterpret_cast<const __half2*>(&ub));
            const float wq = wyv[q & 1] * wzv[q >> 1];
            const float w0 = wxv[0] * wq, w1 = wxv[1] * wq;
            o0 = fmaf(w0, ea.x, o0); o1 = fmaf(w0, ea.y, o1);
            o0 = fmaf(w1, eb.x, o0); o1 = fmaf(w1, eb.y, o1);
        }
        const int pidx = chunk * (BLOCK * PPT1) + s * BLOCK + tid;
        const __half2 ph = __floats2half2_rn(o0, o1);
        wl[pidx] = *(const unsigned*)&ph;   // 4 B coalesced store
    }
}

// ---------------- pass 2: LDS transpose, half2 ws -> f32 out ---------------
__global__ void __launch_bounds__(BLOCK)
hashenc_pass2_h(const unsigned* __restrict__ ws, float* __restrict__ out, int np)
{
    __shared__ float lds[BLOCK * 33];
    const int tid = threadIdx.x;
    const int p0 = blockIdx.x * BLOCK;

#pragma unroll
    for (int l = 0; l < NLEVELS; ++l) {
        const unsigned u = ws[(size_t)l * np + p0 + tid];   // coalesced 4 B/lane
        const float2 v = __half22float2(*reinterpret_cast<const __half2*>(&u));
        lds[tid * 33 + 2 * l + 0] = v.x;    // bank (tid+2l)%32: conflict-free
        lds[tid * 33 + 2 * l + 1] = v.y;
    }
    __syncthreads();
    float* __restrict__ ochunk = out + (size_t)blockIdx.x * (BLOCK * 32);
#pragma unroll
    for (int k = 0; k < 32; ++k) {
        const int flat = k * BLOCK + tid;
        const float v = lds[(flat >> 5) * 33 + (flat & 31)];
        __builtin_nontemporal_store(v, ochunk + flat);
    }
}

// ---------------- tier 2: f32 two-pass --------------------------------------
__global__ void __launch_bounds__(BLOCK)
hashenc_pass1_f32(const float* __restrict__ xyz,
                  const float* __restrict__ emb,
                  float2* __restrict__ ws,
                  HashParams p, int np, int bpl_shift)
{
    const int l = blockIdx.x >> bpl_shift;
    const int chunk = blockIdx.x & ((1 << bpl_shift) - 1);
    const int tid = threadIdx.x;

    __shared__ float sxyz[BLOCK * PPT * 3];
    {
        const float4* __restrict__ src =
            (const float4*)(xyz + (size_t)chunk * (BLOCK * PPT) * 3);
        float4* __restrict__ dst = (float4*)sxyz;
#pragma unroll
        for (int i = tid; i < (BLOCK * PPT * 3) / 4; i += BLOCK)
            dst[i] = src[i];
    }
    __syncthreads();

    const unsigned hs = p.hsize[l];
    const float2* __restrict__ tab = (const float2*)emb + p.offs[l];
    const float scale = (float)((16u << l) - 1u);
    const bool do_hash = (p.hash_bits >> l) & 1u;
    const bool is_pow2 = (p.pow2_bits >> l) & 1u;
    float2* __restrict__ wl = ws + (size_t)l * np;

#pragma unroll
    for (int s = 0; s < PPT; ++s) {
        const int lp = s * BLOCK + tid;
        const int pidx = chunk * (BLOCK * PPT) + lp;
        const float x = sxyz[lp * 3 + 0];
        const float y = sxyz[lp * 3 + 1];
        const float z = sxyz[lp * 3 + 2];
        const float px = x * scale + 0.5f;
        const float py = y * scale + 0.5f;
        const float pz = z * scale + 0.5f;
        const float gx = floorf(px), gy = floorf(py), gz = floorf(pz);
        const float fx = px - gx, fy = py - gy, fz = pz - gz;
        const unsigned ix = (unsigned)gx, iy = (unsigned)gy, iz = (unsigned)gz;
        const float wxv[2] = {1.0f - fx, fx};
        const float wyv[2] = {1.0f - fy, fy};
        const float wzv[2] = {1.0f - fz, fz};
        float o0 = 0.0f, o1 = 0.0f;
        unsigned idx[8];
        if (do_hash) {
            const unsigned hy0 = iy * 2654435761u;
            const unsigned hz0 = iz * 805459861u;
            const unsigned hy1 = hy0 + 2654435761u;
            const unsigned hz1 = hz0 + 805459861u;
            if (is_pow2) {
                const unsigned m = hs - 1u;
#pragma unroll
                for (int c = 0; c < 8; ++c)
                    idx[c] = ((ix + (c & 1)) ^ ((c & 2) ? hy1 : hy0) ^ ((c & 4) ? hz1 : hz0)) & m;
            } else {
#pragma unroll
                for (int c = 0; c < 8; ++c)
                    idx[c] = ((ix + (c & 1)) ^ ((c & 2) ? hy1 : hy0) ^ ((c & 4) ? hz1 : hz0)) % hs;
            }
        } else {
            const unsigned stride = (16u << l) + 1u;
#pragma unroll
            for (int c = 0; c < 8; ++c) {
                const unsigned lin = (ix + (c & 1))
                                   + (iy + ((c >> 1) & 1)) * stride
                                   + (iz + ((c >> 2) & 1)) * stride * stride;
                idx[c] = lin % hs;
            }
        }
        float2 e[8];
#pragma unroll
        for (int c = 0; c < 8; ++c) e[c] = tab[idx[c]];
#pragma unroll
        for (int c = 0; c < 8; ++c) {
            const float w = wxv[c & 1] * wyv[(c >> 1) & 1] * wzv[(c >> 2) & 1];
            o0 = fmaf(w, e[c].x, o0);
            o1 = fmaf(w, e[c].y, o1);
        }
        wl[pidx] = make_float2(o0, o1);
    }
}

__global__ void __launch_bounds__(BLOCK)
hashenc_pass2(const float2* __restrict__ ws, float* __restrict__ out, int np)
{
    __shared__ float lds[BLOCK * 33];
    const int tid = threadIdx.x;
    const int p0 = blockIdx.x * BLOCK;

#pragma unroll
    for (int l = 0; l < NLEVELS; ++l) {
        const float2 v = ws[(size_t)l * np + p0 + tid];
        lds[tid * 33 + 2 * l + 0] = v.x;
        lds[tid * 33 + 2 * l + 1] = v.y;
    }
    __syncthreads();
    float* __restrict__ ochunk = out + (size_t)blockIdx.x * (BLOCK * 32);
#pragma unroll
    for (int k = 0; k < 32; ++k) {
        const int flat = k * BLOCK + tid;
        const float v = lds[(flat >> 5) * 33 + (flat & 31)];
        __builtin_nontemporal_store(v, ochunk + flat);
    }
}

// ---------------- tier 3: single-pass fallback ------------------------------
__global__ void __launch_bounds__(BLOCK)
hashenc_fwd(const float* __restrict__ xyz,
            const float* __restrict__ emb,
            float* __restrict__ out,
            HashParams p)
{
    const int tid = threadIdx.x;
    const long b = (long)blockIdx.x * BLOCK + tid;
    __shared__ float lds[BLOCK * 33];

    const float x = xyz[b * 3 + 0];
    const float y = xyz[b * 3 + 1];
    const float z = xyz[b * 3 + 2];

#pragma unroll
    for (int l = 0; l < NLEVELS; ++l) {
        const float scale = (float)((16u << l) - 1u);
        const float px = x * scale + 0.5f;
        const float py = y * scale + 0.5f;
        const float pz = z * scale + 0.5f;
        const float gx = floorf(px), gy = floorf(py), gz = floorf(pz);
        const float fx = px - gx, fy = py - gy, fz = pz - gz;
        const unsigned ix = (unsigned)gx, iy = (unsigned)gy, iz = (unsigned)gz;
        const unsigned hs = p.hsize[l];
        const float2* __restrict__ tab = (const float2*)emb + p.offs[l];

        unsigned idx[8];
        if ((p.hash_bits >> l) & 1u) {
            const unsigned hy0 = iy * 2654435761u;
            const unsigned hz0 = iz * 805459861u;
            const unsigned hy1 = hy0 + 2654435761u;
            const unsigned hz1 = hz0 + 805459861u;
            if ((p.pow2_bits >> l) & 1u) {
                const unsigned m = hs - 1u;
#pragma unroll
                for (int c = 0; c < 8; ++c)
                    idx[c] = ((ix + (c & 1)) ^ ((c & 2) ? hy1 : hy0) ^ ((c & 4) ? hz1 : hz0)) & m;
            } else {
#pragma unroll
                for (int c = 0; c < 8; ++c)
                    idx[c] = ((ix + (c & 1)) ^ ((c & 2) ? hy1 : hy0) ^ ((c & 4) ? hz1 : hz0)) % hs;
            }
        } else {
            const unsigned stride = (16u << l) + 1u;
#pragma unroll
            for (int c = 0; c < 8; ++c) {
                const unsigned lin = (ix + (c & 1))
                                   + (iy + ((c >> 1) & 1)) * stride
                                   + (iz + ((c >> 2) & 1)) * stride * stride;
                idx[c] = lin % hs;
            }
        }

        float2 e[8];
#pragma unroll
        for (int c = 0; c < 8; ++c) e[c] = tab[idx[c]];

        const float wx[2] = {1.0f - fx, fx};
        const float wy[2] = {1.0f - fy, fy};
        const float wz[2] = {1.0f - fz, fz};
        float o0 = 0.0f, o1 = 0.0f;
#pragma unroll
        for (int c = 0; c < 8; ++c) {
            const float w = wx[c & 1] * wy[(c >> 1) & 1] * wz[(c >> 2) & 1];
            o0 = fmaf(w, e[c].x, o0);
            o1 = fmaf(w, e[c].y, o1);
        }
        lds[tid * 33 + l * 2 + 0] = o0;
        lds[tid * 33 + l * 2 + 1] = o1;
    }

    __syncthreads();
    float* __restrict__ ochunk = out + (long)blockIdx.x * (BLOCK * 32);
#pragma unroll
    for (int k = 0; k < 32; ++k) {
        const int flat = k * BLOCK + tid;
        const float v = lds[(flat >> 5) * 33 + (flat & 31)];
        __builtin_nontemporal_store(v, ochunk + flat);
    }
}

extern "C" void kernel_launch(void* const* d_in, const int* in_sizes, int n_in,
                              void* d_out, int out_size, void* d_ws, size_t ws_size,
                              hipStream_t stream) {
    const float* xyz = (const float*)d_in[0];
    const float* emb = (const float*)d_in[1];
    float* out = (float*)d_out;
    const int B = in_sizes[0] / 3;

    // Reproduce HashEncoder.__init__ offset arithmetic exactly.
    HashParams p;
    p.offs[0] = 0;
    unsigned hash_bits = 0, pow2_bits = 0;
    long off = 0;
    for (int i = 0; i < NLEVELS; ++i) {
        const long res = 16L << i;
        const long dense = (res + 1) * (res + 1) * (res + 1);
        long t = dense < (1L << 19) ? dense : (1L << 19);
        t = (t / 8) * 8;
        p.hsize[i] = (unsigned)t;
        off += t;
        p.offs[i + 1] = (unsigned)off;
        if (dense > t) hash_bits |= (1u << i);   // true for ALL levels here
        if ((t & (t - 1)) == 0) pow2_bits |= (1u << i);
    }
    p.hash_bits = hash_bits;
    p.pow2_bits = pow2_bits;

    const long nent = off;                               // total table entries
    const size_t need_ws16 = (size_t)B * NLEVELS * 4;    // half2 ws (64 MB)
    const size_t need_h = need_ws16 + (size_t)nent * 4;  // + fp16 table (92.6 MB)
    const size_t need_f32 = (size_t)B * NLEVELS * sizeof(float2);
    const bool shape1_ok = (B % (BLOCK * PPT1)) == 0 && (B % BLOCK) == 0;
    const bool shape2_ok = (B % (BLOCK * PPT)) == 0 && (B % BLOCK) == 0;
    const bool all_hashed = (hash_bits == ((1u << NLEVELS) - 1u));

    if (shape1_ok && all_hashed && ws_size >= need_h) {
        // tier 1: fp16 table + half2 ws, PPT=4 deep-MLP pass 1
        unsigned* tab16 = (unsigned*)((char*)d_ws + need_ws16);
        const int n2 = (int)(nent / 2);
        hashenc_conv<<<dim3((n2 + BLOCK - 1) / BLOCK), dim3(BLOCK), 0, stream>>>(
            (const float4*)emb, (uint2*)tab16, n2);
        int bpl_shift = 0;
        while ((1 << bpl_shift) * (BLOCK * PPT1) < B) ++bpl_shift;  // B is pow2
        const int bpl = 1 << bpl_shift;
        hashenc_pass1_h<<<dim3(NLEVELS * bpl), dim3(BLOCK), 0, stream>>>(
            xyz, tab16, (unsigned*)d_ws, p, B, bpl_shift);
        hashenc_pass2_h<<<dim3(B / BLOCK), dim3(BLOCK), 0, stream>>>(
            (const unsigned*)d_ws, out, B);
    } else if (shape2_ok && ws_size >= need_f32) {
        // tier 2: f32 two-pass
        int bpl_shift = 0;
        while ((1 << bpl_shift) * (BLOCK * PPT) < B) ++bpl_shift;
        const int bpl = 1 << bpl_shift;
        hashenc_pass1_f32<<<dim3(NLEVELS * bpl), dim3(BLOCK), 0, stream>>>(
            xyz, emb, (float2*)d_ws, p, B, bpl_shift);
        hashenc_pass2<<<dim3(B / BLOCK), dim3(BLOCK), 0, stream>>>(
            (const float2*)d_ws, out, B);
    } else {
        // tier 3: single-pass fallback
        hashenc_fwd<<<dim3(B / BLOCK), dim3(BLOCK), 0, stream>>>(xyz, emb, out, p);
    }
}